// Round 7
// baseline (7306.428 us; speedup 1.0000x reference)
//
#include <hip/hip_runtime.h>
#include <stdint.h>

typedef _Float16 half8 __attribute__((ext_vector_type(8)));
typedef float    f32x4 __attribute__((ext_vector_type(4)));
typedef uint32_t u4    __attribute__((ext_vector_type(4)));

// tanh(z) = 1 - 2/(exp(2z)+1); v_exp_f32 + v_rcp path.
__device__ __forceinline__ float fast_tanh(float z) {
    float e = __expf(2.0f * z);
    return 1.0f - 2.0f * __builtin_amdgcn_rcpf(e + 1.0f);
}

#define TT 4096
#define NB 32
#define HD 512
#define NW 8               // waves per block
#define CT 4               // col-tiles (16 cols) per wave -> 64 cols/wave
#define RT 3               // col-tiles whose B-frags live in registers
#define KK 16              // K=512 / 32 per MFMA

// One block per batch row (rows are independent recurrences). 8 waves; wave w
// owns output cols [w*64, w*64+64) as 4 MFMA col-tiles and contracts the FULL
// K=512 itself -> no k-group split, no pads reduce, ONE barrier per step.
//
// Matrix pipe does the matvec: mfma_f32_16x16x32_f16 with M=1 useful row
// (state broadcast to all 16 A-rows). Even at 1/16 M-utilization the MFMA
// pipe delivers ~211 useful FLOP/cyc/SIMD vs dot2's 64 (rounds 2-6 showed
// VALU pinned at fp32 rate) -> dot phase 2048 -> ~620 cyc/SIMD.
//
// W_int is pre-packed into B-fragments (fp16): per wave 4 col-tiles x 16
// kk-steps; tiles 0..2 in registers (192 words -- AGPR-resident is FINE,
// MFMA reads AGPRs natively), tile 3 in LDS (128 KB, conflict-free b128).
// A-fragment for kk: lane l needs state[kk*32 + (l>>4)*8 .. +7] = one b128
// at 4 distinct addresses/wave (16-lane broadcast groups, banks 0..15
// disjoint). k-order consistency: A and B packings use the same (l>>4, j)
// -> k map, so any hardware k-permutation cancels (A/B layouts symmetric).
//
// Epilogue: D rows are all equal (A rows replicated); lanes 0..15 hold
// row 0 in acc[0] -> z = acc + W_in.x + noise, tanh, publish fp16 state to
// LDS + stash out-value in regs. Out stores are issued at the TOP of the
// next step so their vmcnt drain hides under the MFMA phase.
__global__ __launch_bounds__(512, 1)
void esn_kernel(const float* __restrict__ X, const float* __restrict__ W_in,
                const float* __restrict__ W_int, const float* __restrict__ noise,
                float* __restrict__ out)
{
    __shared__ __align__(16) _Float16 s_buf[2][HD];   // 2 KB state (fp16, dbuf)
    __shared__ u4 wstashB[NW * KK * 64];              // 128 KB: col-tile 3 B-frags
    __shared__ float win_lds[HD][3];                  // 6 KB input weights

    const int tid = threadIdx.x;
    const int b   = blockIdx.x;
    const int w   = tid >> 6;      // wave 0..7
    const int l   = tid & 63;      // lane 0..63
    const int lg  = l >> 4;        // k-subgroup 0..3
    const int lc  = l & 15;        // col within 16-col tile

    win_lds[tid < HD ? tid : 0][0] = W_in[(tid < HD ? tid : 0)*3 + 0];
    win_lds[tid < HD ? tid : 0][1] = W_in[(tid < HD ? tid : 0)*3 + 1];
    win_lds[tid < HD ? tid : 0][2] = W_in[(tid < HD ? tid : 0)*3 + 2];

    // ---- Prologue: pack W_int (fp32 [k][h]) into fp16 B-fragments ----
    // B-frag (ct, kk): lane l, slot j -> W_int[kk*32 + lg*8 + j][w*64+ct*16+lc]
    half8 wregB[RT][KK];           // 192 reg words; static indices only
    #pragma unroll
    for (int ct = 0; ct < CT; ++ct) {
        const int col = w*64 + ct*16 + lc;
        #pragma unroll
        for (int kk = 0; kk < KK; ++kk) {
            const int kb = kk*32 + lg*8;
            half8 hb;
            #pragma unroll
            for (int j = 0; j < 8; ++j)
                hb[j] = (_Float16)W_int[(size_t)(kb + j)*HD + col];
            if (ct < RT) wregB[ct][kk] = hb;
            else         wstashB[(w*KK + kk)*64 + l] = __builtin_bit_cast(u4, hb);
        }
    }
    s_buf[0][tid & (HD-1)] = (_Float16)0.01f;   // prev0 = 0.01 (512 thr = HD)
    __syncthreads();

    const float* Xb   = X   + (size_t)b * TT * 3;
    float*       outb = out + (size_t)b * TT * HD;

    float sval0 = 0.f, sval1 = 0.f, sval2 = 0.f, sval3 = 0.f;
    int cur = 0;
    for (int t = 0; t < TT; ++t) {
        // ---- step top: store step t-1 outputs, load step t noise ----
        float nz0 = 0.f, nz1 = 0.f, nz2 = 0.f, nz3 = 0.f;
        if (l < 16) {
            if (t > 0) {
                float* op = outb + (size_t)(t-1)*HD + w*64 + l;
                op[0] = sval0; op[16] = sval1; op[32] = sval2; op[48] = sval3;
            }
            const float* np = noise + ((size_t)t*NB + b)*HD + w*64 + l;
            nz0 = np[0]; nz1 = np[16]; nz2 = np[32]; nz3 = np[48];
        }
        const float x0 = Xb[t*3 + 0];
        const float x1 = Xb[t*3 + 1];
        const float x2 = Xb[t*3 + 2];

        // ---- MFMA phase: 4 independent acc chains over 16 kk-steps ----
        f32x4 acc0{}, acc1{}, acc2{}, acc3{};
        const u4* abase = (const u4*)(&s_buf[cur][0]);
        #pragma unroll
        for (int kk = 0; kk < KK; ++kk) {
            const half8 af = __builtin_bit_cast(half8, abase[kk*4 + lg]);
            const half8 b3 = __builtin_bit_cast(half8, wstashB[(w*KK + kk)*64 + l]);
            acc0 = __builtin_amdgcn_mfma_f32_16x16x32_f16(af, wregB[0][kk], acc0, 0, 0, 0);
            acc1 = __builtin_amdgcn_mfma_f32_16x16x32_f16(af, wregB[1][kk], acc1, 0, 0, 0);
            acc2 = __builtin_amdgcn_mfma_f32_16x16x32_f16(af, wregB[2][kk], acc2, 0, 0, 0);
            acc3 = __builtin_amdgcn_mfma_f32_16x16x32_f16(af, b3,           acc3, 0, 0, 0);
        }

        // ---- epilogue: lanes 0..15 own cols w*64 + {0,16,32,48} + l ----
        if (l < 16) {
            const int c0 = w*64 + l;
            float z0 = acc0[0] + win_lds[c0   ][0]*x0 + win_lds[c0   ][1]*x1 + win_lds[c0   ][2]*x2 + 0.01f*nz0;
            float z1 = acc1[0] + win_lds[c0+16][0]*x0 + win_lds[c0+16][1]*x1 + win_lds[c0+16][2]*x2 + 0.01f*nz1;
            float z2 = acc2[0] + win_lds[c0+32][0]*x0 + win_lds[c0+32][1]*x1 + win_lds[c0+32][2]*x2 + 0.01f*nz2;
            float z3 = acc3[0] + win_lds[c0+48][0]*x0 + win_lds[c0+48][1]*x1 + win_lds[c0+48][2]*x2 + 0.01f*nz3;
            sval0 = fast_tanh(z0);
            sval1 = fast_tanh(z1);
            sval2 = fast_tanh(z2);
            sval3 = fast_tanh(z3);
            s_buf[cur^1][c0     ] = (_Float16)sval0;
            s_buf[cur^1][c0 + 16] = (_Float16)sval1;
            s_buf[cur^1][c0 + 32] = (_Float16)sval2;
            s_buf[cur^1][c0 + 48] = (_Float16)sval3;
        }
        __syncthreads();   // ONE barrier per step
        cur ^= 1;
    }
    // flush final step's outputs
    if (l < 16) {
        float* op = outb + (size_t)(TT-1)*HD + w*64 + l;
        op[0] = sval0; op[16] = sval1; op[32] = sval2; op[48] = sval3;
    }
}

extern "C" void kernel_launch(void* const* d_in, const int* in_sizes, int n_in,
                              void* d_out, int out_size, void* d_ws, size_t ws_size,
                              hipStream_t stream)
{
    const float* X     = (const float*)d_in[0];
    const float* W_in  = (const float*)d_in[1];
    const float* W_int = (const float*)d_in[2];
    const float* noise = (const float*)d_in[3];
    float* out = (float*)d_out;

    esn_kernel<<<dim3(NB), dim3(512), 0, stream>>>(X, W_in, W_int, noise, out);
}